// Round 1
// baseline (98.968 us; speedup 1.0000x reference)
//
#include <hip/hip_runtime.h>

// Decoder: frames[m,c,k,l] = sum_n (mix[m,n,k]*mask[m,c,n,k]) * W[l,n]
// then overlap-add (hop=8) into out[m,c,t], T = (K-1)*8+16 = 128008.
// M=4 C=2 N=512 K=16000 L=16.

#define M_   4
#define C_   2
#define N_   512
#define K_   16000
#define L_   16
#define HOP  8
#define T_   ((K_ - 1) * HOP + L_)   // 128008
#define BK   64                      // k-frames per block (one per lane)
#define NSEG 4                       // waves per block, each owns N_/NSEG n's
#define NPW  (N_ / NSEG)             // 128

__global__ __launch_bounds__(256, 4)
void decoder_kernel(const float* __restrict__ mix,   // [M][N][K]
                    const float* __restrict__ mask,  // [M][C][N][K]
                    const float* __restrict__ Wg,    // [L][N]
                    float* __restrict__ out) {       // [M][C][T]
    // Phase A: W staged as [L][N] (32 KB). Phase B (after loop): reduction
    // buffer red[3][64][36] floats (stride 36 = 16B-aligned, non-pow2 bank).
    __shared__ float lds[8192];

    const int tid  = threadIdx.x;
    const int lane = tid & 63;
    const int w    = tid >> 6;                 // wave id = n-segment
    const int m    = blockIdx.x / (K_ / BK);
    const int k0   = (blockIdx.x % (K_ / BK)) * BK;

    // ---- stage W into LDS (coalesced global read, linear LDS write) ----
    for (int i = tid; i < L_ * N_; i += 256) lds[i] = Wg[i];
    __syncthreads();

    float acc[32];                             // acc[c*16 + l]
    #pragma unroll
    for (int i = 0; i < 32; ++i) acc[i] = 0.f;

    const int n0w = w * NPW;
    const float* pm = mix  + (size_t)m * N_ * K_ + (size_t)n0w * K_ + (k0 + lane);
    const float* p0 = mask + (size_t)(m * C_) * N_ * K_ + (size_t)n0w * K_ + (k0 + lane);
    const float* p1 = p0 + (size_t)N_ * K_;

    // ---- main loop: 32 chunks of 4 n's ----
    for (int ch = 0; ch < NPW / 4; ++ch) {
        float mv[4], a0[4], a1[4];
        #pragma unroll
        for (int j = 0; j < 4; ++j) {
            mv[j] = pm[(size_t)j * K_];
            a0[j] = p0[(size_t)j * K_];
            a1[j] = p1[(size_t)j * K_];
        }
        float s0[4], s1[4];
        #pragma unroll
        for (int j = 0; j < 4; ++j) { s0[j] = mv[j] * a0[j]; s1[j] = mv[j] * a1[j]; }

        const int nbase = n0w + ch * 4;
        #pragma unroll
        for (int l = 0; l < L_; ++l) {
            const float4 w4 = *(const float4*)&lds[l * N_ + nbase];  // uniform -> broadcast
            acc[l]      = fmaf(s0[0], w4.x, acc[l]);
            acc[l]      = fmaf(s0[1], w4.y, acc[l]);
            acc[l]      = fmaf(s0[2], w4.z, acc[l]);
            acc[l]      = fmaf(s0[3], w4.w, acc[l]);
            acc[16 + l] = fmaf(s1[0], w4.x, acc[16 + l]);
            acc[16 + l] = fmaf(s1[1], w4.y, acc[16 + l]);
            acc[16 + l] = fmaf(s1[2], w4.z, acc[16 + l]);
            acc[16 + l] = fmaf(s1[3], w4.w, acc[16 + l]);
        }
        pm += (size_t)4 * K_;
        p0 += (size_t)4 * K_;
        p1 += (size_t)4 * K_;
    }

    // ---- cross-wave reduction through LDS (reuses W region; W dead now) ----
    __syncthreads();
    if (w > 0) {
        float* rb = &lds[(w - 1) * 2304 + lane * 36];
        #pragma unroll
        for (int i = 0; i < 8; ++i)
            *(float4*)&rb[i * 4] =
                make_float4(acc[i*4], acc[i*4+1], acc[i*4+2], acc[i*4+3]);
    }
    __syncthreads();

    if (w == 0) {
        #pragma unroll
        for (int r = 0; r < 3; ++r) {
            const float* rb = &lds[r * 2304 + lane * 36];
            #pragma unroll
            for (int i = 0; i < 8; ++i) {
                const float4 v = *(const float4*)&rb[i * 4];
                acc[i*4]     += v.x;
                acc[i*4 + 1] += v.y;
                acc[i*4 + 2] += v.z;
                acc[i*4 + 3] += v.w;
            }
        }

        // ---- overlap-add, in-register via shfl_up ----
        // sample t = k*8 + j  (j in 0..7) = frames[k][j] + frames[k-1][j+8]
        #pragma unroll
        for (int c = 0; c < C_; ++c) {
            float* ob = out + (size_t)(m * C_ + c) * T_ + (size_t)(k0 + lane) * HOP;
            float cmb[8];
            #pragma unroll
            for (int j = 0; j < 8; ++j) {
                const float pv = __shfl_up(acc[c * 16 + 8 + j], 1);
                cmb[j] = acc[c * 16 + j] + pv;
            }
            if (lane == 0) {
                // frames[k0-1] lives in the previous block -> atomic partial
                #pragma unroll
                for (int j = 0; j < 8; ++j) atomicAdd(&ob[j], acc[c * 16 + j]);
            } else {
                *(float4*)&ob[0] = make_float4(cmb[0], cmb[1], cmb[2], cmb[3]);
                *(float4*)&ob[4] = make_float4(cmb[4], cmb[5], cmb[6], cmb[7]);
            }
            if (lane == 63) {
                // this block's high tail -> next block's lane-0 region
                #pragma unroll
                for (int j = 0; j < 8; ++j)
                    atomicAdd(&ob[8 + j], acc[c * 16 + 8 + j]);
            }
        }
    }
}

extern "C" void kernel_launch(void* const* d_in, const int* in_sizes, int n_in,
                              void* d_out, int out_size, void* d_ws, size_t ws_size,
                              hipStream_t stream) {
    const float* mix  = (const float*)d_in[0];
    const float* mask = (const float*)d_in[1];
    const float* Wg   = (const float*)d_in[2];
    float* out = (float*)d_out;

    // Harness poisons d_out once and never re-poisons between replays; the
    // boundary atomics accumulate, so zero the output every call (capture-safe).
    hipMemsetAsync(d_out, 0, (size_t)out_size * sizeof(float), stream);

    decoder_kernel<<<dim3(M_ * (K_ / BK)), dim3(256), 0, stream>>>(mix, mask, Wg, out);
}

// Round 2
// 97.471 us; speedup vs baseline: 1.0154x; 1.0154x over previous
//
#include <hip/hip_runtime.h>

// Decoder: frames[m,c,k,l] = sum_n (mix[m,n,k]*mask[m,c,n,k]) * W[l,n]
// then overlap-add (hop=8) into out[m,c,t], T = (K-1)*8+16 = 128008.
// M=4 C=2 N=512 K=16000 L=16.
//
// Structure: block = (m, 64 consecutive frames k), 4 waves each owning 128 n's.
// lane = k offset (coalesced 256B global loads). W staged in LDS, read at
// wave-uniform addresses (broadcast). Cross-wave reduce through LDS, then
// wave 0 does the overlap-add in-register via shfl_up. Block-boundary samples
// (8 head + 8 tail per block) go to d_ws; a tiny second kernel combines them,
// so every output element is written exactly once with '=' -> no memset, no
// atomics, deterministic across graph replays.

#define M_   4
#define C_   2
#define N_   512
#define K_   16000
#define L_   16
#define HOP  8
#define T_   ((K_ - 1) * HOP + L_)   // 128008
#define BK   64                      // k-frames per block (one per lane)
#define NSEG 4                       // waves per block, each owns N_/NSEG n's
#define NPW  (N_ / NSEG)             // 128
#define NB   (K_ / BK)               // 250 blocks per m
#define WS_TAIL_OFF (M_ * C_ * NB * 8)   // floats; heads then tails

__global__ __launch_bounds__(256, 4)
void decoder_kernel(const float* __restrict__ mix,   // [M][N][K]
                    const float* __restrict__ mask,  // [M][C][N][K]
                    const float* __restrict__ Wg,    // [L][N]
                    float* __restrict__ out,         // [M][C][T]
                    float* __restrict__ ws) {        // head/tail partials
    __shared__ float lds[8192];      // W [16][512] = 32 KB; reused for reduce

    const int tid  = threadIdx.x;
    const int lane = tid & 63;
    const int w    = tid >> 6;                 // wave id = n-segment
    const int m    = blockIdx.x / NB;
    const int bb   = blockIdx.x % NB;
    const int k0   = bb * BK;

    // ---- stage W into LDS (coalesced global read, linear LDS write) ----
    for (int i = tid; i < L_ * N_; i += 256) lds[i] = Wg[i];
    __syncthreads();

    float acc[32];                             // acc[c*16 + l]
    #pragma unroll
    for (int i = 0; i < 32; ++i) acc[i] = 0.f;

    const int n0w = w * NPW;
    const float* pm = mix  + (size_t)m * N_ * K_ + (size_t)n0w * K_ + (k0 + lane);
    const float* p0 = mask + (size_t)(m * C_) * N_ * K_ + (size_t)n0w * K_ + (k0 + lane);
    const float* p1 = p0 + (size_t)N_ * K_;

    // ---- main loop: 32 chunks of 4 n's (unroll 2 -> 24 loads in flight) ----
    #pragma unroll 2
    for (int ch = 0; ch < NPW / 4; ++ch) {
        float mv[4], a0[4], a1[4];
        #pragma unroll
        for (int j = 0; j < 4; ++j) {
            mv[j] = pm[(size_t)j * K_];
            a0[j] = p0[(size_t)j * K_];
            a1[j] = p1[(size_t)j * K_];
        }
        float s0[4], s1[4];
        #pragma unroll
        for (int j = 0; j < 4; ++j) { s0[j] = mv[j] * a0[j]; s1[j] = mv[j] * a1[j]; }

        const int nbase = n0w + ch * 4;
        #pragma unroll
        for (int l = 0; l < L_; ++l) {
            const float4 w4 = *(const float4*)&lds[l * N_ + nbase];  // uniform -> broadcast
            acc[l]      = fmaf(s0[0], w4.x, acc[l]);
            acc[l]      = fmaf(s0[1], w4.y, acc[l]);
            acc[l]      = fmaf(s0[2], w4.z, acc[l]);
            acc[l]      = fmaf(s0[3], w4.w, acc[l]);
            acc[16 + l] = fmaf(s1[0], w4.x, acc[16 + l]);
            acc[16 + l] = fmaf(s1[1], w4.y, acc[16 + l]);
            acc[16 + l] = fmaf(s1[2], w4.z, acc[16 + l]);
            acc[16 + l] = fmaf(s1[3], w4.w, acc[16 + l]);
        }
        pm += (size_t)4 * K_;
        p0 += (size_t)4 * K_;
        p1 += (size_t)4 * K_;
    }

    // ---- cross-wave reduction through LDS (reuses W region; W dead now) ----
    __syncthreads();
    if (w > 0) {
        float* rb = &lds[(w - 1) * 2304 + lane * 36];
        #pragma unroll
        for (int i = 0; i < 8; ++i)
            *(float4*)&rb[i * 4] =
                make_float4(acc[i*4], acc[i*4+1], acc[i*4+2], acc[i*4+3]);
    }
    __syncthreads();

    if (w == 0) {
        #pragma unroll
        for (int r = 0; r < 3; ++r) {
            const float* rb = &lds[r * 2304 + lane * 36];
            #pragma unroll
            for (int i = 0; i < 8; ++i) {
                const float4 v = *(const float4*)&rb[i * 4];
                acc[i*4]     += v.x;
                acc[i*4 + 1] += v.y;
                acc[i*4 + 2] += v.z;
                acc[i*4 + 3] += v.w;
            }
        }

        // ---- overlap-add: sample t=k*8+j = frames[k][j] + frames[k-1][8+j] ----
        #pragma unroll
        for (int c = 0; c < C_; ++c) {
            float* ob = out + (size_t)(m * C_ + c) * T_ + (size_t)(k0 + lane) * HOP;
            float cmb[8];
            #pragma unroll
            for (int j = 0; j < 8; ++j) {
                const float pv = __shfl_up(acc[c * 16 + 8 + j], 1);
                cmb[j] = acc[c * 16 + j] + pv;
            }
            if (lane == 0) {
                // head partial: frames[k0][0..7] -> combined by fixup kernel
                float* hb = ws + (size_t)((m * C_ + c) * NB + bb) * 8;
                *(float4*)&hb[0] = make_float4(acc[c*16+0], acc[c*16+1], acc[c*16+2], acc[c*16+3]);
                *(float4*)&hb[4] = make_float4(acc[c*16+4], acc[c*16+5], acc[c*16+6], acc[c*16+7]);
            } else {
                *(float4*)&ob[0] = make_float4(cmb[0], cmb[1], cmb[2], cmb[3]);
                *(float4*)&ob[4] = make_float4(cmb[4], cmb[5], cmb[6], cmb[7]);
            }
            if (lane == 63) {
                // tail partial: frames[k0+63][8..15]
                float* tb = ws + WS_TAIL_OFF + (size_t)((m * C_ + c) * NB + bb) * 8;
                *(float4*)&tb[0] = make_float4(acc[c*16+8],  acc[c*16+9],  acc[c*16+10], acc[c*16+11]);
                *(float4*)&tb[4] = make_float4(acc[c*16+12], acc[c*16+13], acc[c*16+14], acc[c*16+15]);
            }
        }
    }
}

// Combine boundary partials: out[b*512 + j] = head[b] + tail[b-1] (tail only
// if b>0); the global tail (t=128000..128007) = tail[NB-1].
__global__ __launch_bounds__(256)
void boundary_kernel(const float* __restrict__ ws, float* __restrict__ out) {
    const int id = blockIdx.x * 256 + threadIdx.x;
    const int total = M_ * C_ * NB * 8;
    if (id >= total) return;
    const int j  = id & 7;
    const int bb = (id >> 3) % NB;
    const int mc = (id >> 3) / NB;            // m*C + c
    float v = ws[(size_t)(mc * NB + bb) * 8 + j];
    if (bb > 0) v += ws[WS_TAIL_OFF + (size_t)(mc * NB + bb - 1) * 8 + j];
    out[(size_t)mc * T_ + (size_t)bb * (BK * HOP) + j] = v;
    if (bb == NB - 1) {
        out[(size_t)mc * T_ + (size_t)K_ * HOP + j] =
            ws[WS_TAIL_OFF + (size_t)(mc * NB + bb) * 8 + j];
    }
}

extern "C" void kernel_launch(void* const* d_in, const int* in_sizes, int n_in,
                              void* d_out, int out_size, void* d_ws, size_t ws_size,
                              hipStream_t stream) {
    const float* mix  = (const float*)d_in[0];
    const float* mask = (const float*)d_in[1];
    const float* Wg   = (const float*)d_in[2];
    float* out = (float*)d_out;
    float* ws  = (float*)d_ws;

    decoder_kernel<<<dim3(M_ * NB), dim3(256), 0, stream>>>(mix, mask, Wg, out, ws);
    boundary_kernel<<<dim3((M_ * C_ * NB * 8 + 255) / 256), dim3(256), 0, stream>>>(ws, out);
}